// Round 3
// baseline (6463.034 us; speedup 1.0000x reference)
//
#include <hip/hip_runtime.h>

typedef unsigned int u32;
typedef unsigned short u16;
typedef __attribute__((ext_vector_type(2))) _Float16 h2v;
typedef __attribute__((ext_vector_type(4))) _Float16 f16x4;
typedef __attribute__((ext_vector_type(4))) float f32x4;

#define BB 32
#define TT 2048
#define CC 256
#define ESZ 256
#define GG 1024   // 4*es

#define QREG 23   // h-quad groups (4 half2-rows each) sourced from registers: rows 0..91
#define QLDS 9    // groups sourced from LDS: rows 92..127 (36 rows, 144 KB)

// ---------------- helpers ----------------
__device__ __forceinline__ float fdot2u(u32 a, u32 b, float c) {
#if __has_builtin(__builtin_amdgcn_fdot2)
  return __builtin_amdgcn_fdot2(__builtin_bit_cast(h2v, a), __builtin_bit_cast(h2v, b), c, false);
#else
  h2v av = __builtin_bit_cast(h2v, a), bv = __builtin_bit_cast(h2v, b);
  return c + (float)av[0] * (float)bv[0] + (float)av[1] * (float)bv[1];
#endif
}

__device__ __forceinline__ float sigm_f(float x) {
  float e = __builtin_amdgcn_exp2f(x * -1.442695041f);
  return __builtin_amdgcn_rcpf(1.0f + e);
}
__device__ __forceinline__ float tanh_f(float x) {
  float e = __builtin_amdgcn_exp2f(x * 2.885390082f);  // exp(2x)
  return 1.0f - 2.0f * __builtin_amdgcn_rcpf(e + 1.0f);
}

// ---------------- kernel 0: pack W2 (f32 [256][1024] -> f16-pair [128][1024]) ----------------
__global__ void k_pack_w2(const float* __restrict__ W2, u32* __restrict__ W2p) {
  int gid = blockIdx.x * 256 + threadIdx.x;   // m = gid>>10, j = gid&1023
  int m = gid >> 10, j = gid & 1023;
  _Float16 lo = (_Float16)W2[(size_t)(2 * m) * GG + j];
  _Float16 hi = (_Float16)W2[(size_t)(2 * m + 1) * GG + j];
  W2p[gid] = (u32)__builtin_bit_cast(u16, lo) | ((u32)__builtin_bit_cast(u16, hi) << 16);
}

// ---------------- kernel 1: pre = x@W1 + b1 + b2  (f16 MFMA, out f16 [B*T][1024]) ----------------
__global__ __launch_bounds__(256, 2) void k_pre_gemm(
    const float* __restrict__ x, const float* __restrict__ W1,
    const float* __restrict__ b1, const float* __restrict__ b2,
    _Float16* __restrict__ pre) {
  __shared__ __attribute__((aligned(16))) _Float16 Al[128 * 36];
  __shared__ __attribute__((aligned(16))) _Float16 Bl[64 * 36];
  const int tid = threadIdx.x;
  const int lane = tid & 63, wv = tid >> 6;
  const int wr = wv >> 1, wc = wv & 1;
  const int rowBase = blockIdx.x * 128;
  const int colBase = blockIdx.y * 64;

  f32x4 acc[4][2];
#pragma unroll
  for (int mi = 0; mi < 4; ++mi)
#pragma unroll
    for (int ni = 0; ni < 2; ++ni) acc[mi][ni] = (f32x4){0.f, 0.f, 0.f, 0.f};

  for (int k0 = 0; k0 < 256; k0 += 32) {
#pragma unroll
    for (int i = 0; i < 4; ++i) {
      int fidx = tid + 256 * i;
      int row = fidx >> 3, kc = (fidx & 7) * 4;
      const float4 v = *(const float4*)(x + (size_t)(rowBase + row) * 256 + k0 + kc);
      f16x4 hv = { (_Float16)v.x, (_Float16)v.y, (_Float16)v.z, (_Float16)v.w };
      *(f16x4*)&Al[row * 36 + kc] = hv;
    }
#pragma unroll
    for (int i = 0; i < 8; ++i) {
      int idx = tid + 256 * i;
      int k = idx >> 6, n = idx & 63;
      Bl[n * 36 + k] = (_Float16)W1[(size_t)(k0 + k) * GG + colBase + n];
    }
    __syncthreads();

#pragma unroll
    for (int kk = 0; kk < 2; ++kk) {
      int ka = (lane >> 4) * 4 + kk * 16;
      f16x4 af[4], bf[2];
#pragma unroll
      for (int mi = 0; mi < 4; ++mi)
        af[mi] = *(const f16x4*)&Al[(wr * 64 + mi * 16 + (lane & 15)) * 36 + ka];
#pragma unroll
      for (int ni = 0; ni < 2; ++ni)
        bf[ni] = *(const f16x4*)&Bl[(wc * 32 + ni * 16 + (lane & 15)) * 36 + ka];
#pragma unroll
      for (int mi = 0; mi < 4; ++mi)
#pragma unroll
        for (int ni = 0; ni < 2; ++ni)
          acc[mi][ni] = __builtin_amdgcn_mfma_f32_16x16x16f16(af[mi], bf[ni], acc[mi][ni], 0, 0, 0);
    }
    __syncthreads();
  }

#pragma unroll
  for (int ni = 0; ni < 2; ++ni) {
    int col = colBase + wc * 32 + ni * 16 + (lane & 15);
    float bias = b1[col] + b2[col];
#pragma unroll
    for (int mi = 0; mi < 4; ++mi) {
      int r0 = rowBase + wr * 64 + mi * 16 + (lane >> 4) * 4;
#pragma unroll
      for (int rr = 0; rr < 4; ++rr)
        pre[(size_t)(r0 + rr) * GG + col] = (_Float16)(acc[mi][ni][rr] + bias);
    }
  }
}

// ---------------- kernel 2: the recurrence ----------------
// 32 blocks (one per batch), 1024 threads (16 waves, 4/SIMD, <=128 VGPR).
// Thread t owns gate column t. W2 column: rows 0..91 (as half2) in 92 VGPRs,
// rows 92..127 in LDS (9 uint4 chunks). h broadcast via same-address
// ds_read_b128. Gate exchange via LDS [4][260]; waves 0..3 update c/h.
__global__ __launch_bounds__(1024, 4) void k_lstm_rec(
    const _Float16* __restrict__ pre, const u32* __restrict__ W2p,
    const float* __restrict__ h0, const float* __restrict__ c0,
    float* __restrict__ out1, float* __restrict__ out2,
    float* __restrict__ hN, float* __restrict__ cN) {
  extern __shared__ __attribute__((aligned(16))) char smem[];
  uint4* W2Lw = (uint4*)smem;                                    // 9*1024 uint4 = 144 KB
  const uint4* W2L = (const uint4*)smem;
  _Float16* hbuf = (_Float16*)(smem + QLDS * 1024 * 16);         // 256 f16 = 512 B
  const uint4* hrow4 = (const uint4*)(smem + QLDS * 1024 * 16);  // h as 32 uint4
  float* exch = (float*)(smem + QLDS * 1024 * 16 + 512);         // [4][260] f32

  const int t = threadIdx.x;     // gate column 0..1023
  const int b = blockIdx.x;
  const int j = t & 255;         // es index
  const int gate = t >> 8;       // 0:f 1:i 2:o 3:ch

  // register-resident W2 rows 0..91 for this column
  u32 w[QREG * 4];
#pragma unroll
  for (int m = 0; m < QREG * 4; ++m) w[m] = W2p[m * GG + t];
#pragma unroll
  for (int m = 0; m < QREG * 4; ++m) asm volatile("" : "+v"(w[m]));  // pin in VGPRs

  // LDS-resident rows 92..127: chunk i holds rows 92+4i..92+4i+3, own column only
#pragma unroll
  for (int i = 0; i < QLDS; ++i) {
    int m0 = QREG * 4 + 4 * i;
    uint4 v;
    v.x = W2p[(m0 + 0) * GG + t];
    v.y = W2p[(m0 + 1) * GG + t];
    v.z = W2p[(m0 + 2) * GG + t];
    v.w = W2p[(m0 + 3) * GG + t];
    W2Lw[i * 1024 + t] = v;
  }

  float creg = 0.f, hlast = 0.f;
  if (t < ESZ) {
    hbuf[t] = (_Float16)h0[b * ESZ + t];
    creg = c0[b * ESZ + t];
  }
  __syncthreads();

  const _Float16* preB = pre + (size_t)b * TT * GG;
  _Float16 q = preB[t];

  for (int s = 0; s < TT; ++s) {
    float a0 = 0.f, a1 = 0.f;

#pragma unroll
    for (int qq = 0; qq < 32; ++qq) {
      uint4 hh = hrow4[qq];                       // broadcast: all lanes same addr
      u32 hx[4] = {hh.x, hh.y, hh.z, hh.w};
      if (qq < QREG) {
        a0 = fdot2u(hx[0], w[4 * qq + 0], a0);
        a1 = fdot2u(hx[1], w[4 * qq + 1], a1);
        a0 = fdot2u(hx[2], w[4 * qq + 2], a0);
        a1 = fdot2u(hx[3], w[4 * qq + 3], a1);
      } else {
        uint4 wv = W2L[(qq - QREG) * 1024 + t];   // per-lane stride-16B, conflict-free
        a0 = fdot2u(hx[0], wv.x, a0);
        a1 = fdot2u(hx[1], wv.y, a1);
        a0 = fdot2u(hx[2], wv.z, a0);
        a1 = fdot2u(hx[3], wv.w, a1);
      }
    }

    float v = (float)q + a0 + a1;
    if (s + 1 < TT) q = preB[(size_t)(s + 1) * GG + t];  // prefetch next pre

    float g = (gate == 3) ? tanh_f(v) : sigm_f(v);       // wave-uniform branch
    exch[gate * 260 + j] = g;
    __syncthreads();  // B1: exch ready; all h reads of this step done

    if (t < ESZ) {
      float fg = exch[0 * 260 + t];
      float ig = exch[1 * 260 + t];
      float og = exch[2 * 260 + t];
      float ch = exch[3 * 260 + t];
      creg = fg * creg + ig * ch;
      float hv = og * tanh_f(creg);
      hlast = hv;
      out1[(size_t)b * TT * ESZ + (size_t)s * ESZ + t] = hv;   // [B, T*es]
      out2[(size_t)s * (BB * ESZ) + b * ESZ + t] = hv;         // [T, B, es]
      hbuf[t] = (_Float16)hv;
    }
    __syncthreads();  // B2: next step's h visible
  }

  if (t < ESZ) {
    hN[b * ESZ + t] = hlast;
    cN[b * ESZ + t] = creg;
  }
}

// ---------------- launch ----------------
extern "C" void kernel_launch(void* const* d_in, const int* in_sizes, int n_in,
                              void* d_out, int out_size, void* d_ws, size_t ws_size,
                              hipStream_t stream) {
  const float* x  = (const float*)d_in[0];
  const float* h0 = (const float*)d_in[1];
  const float* c0 = (const float*)d_in[2];
  const float* W1 = (const float*)d_in[3];
  const float* W2 = (const float*)d_in[4];
  const float* b1 = (const float*)d_in[5];
  const float* b2 = (const float*)d_in[6];

  float* out1 = (float*)d_out;
  float* out2 = out1 + (size_t)BB * TT * ESZ;
  float* hN   = out2 + (size_t)BB * TT * ESZ;
  float* cN   = hN + BB * ESZ;

  _Float16* pre = (_Float16*)d_ws;                                  // 128 MB
  u32* W2p = (u32*)((char*)d_ws + (size_t)BB * TT * GG * 2);        // 512 KB

  k_pack_w2<<<512, 256, 0, stream>>>(W2, W2p);
  k_pre_gemm<<<dim3(512, 16), 256, 0, stream>>>(x, W1, b1, b2, pre);

  const int ldsBytes = QLDS * 1024 * 16 + 512 + 4 * 260 * 4;  // W2 tail + hbuf + exch
  hipFuncSetAttribute((const void*)k_lstm_rec, hipFuncAttributeMaxDynamicSharedMemorySize, ldsBytes);
  k_lstm_rec<<<BB, 1024, ldsBytes, stream>>>(pre, W2p, h0, c0, out1, out2, hN, cN);
}

// Round 4
// 5230.545 us; speedup vs baseline: 1.2356x; 1.2356x over previous
//
#include <hip/hip_runtime.h>

typedef unsigned int u32;
typedef unsigned short u16;
typedef __attribute__((ext_vector_type(2))) _Float16 h2v;
typedef __attribute__((ext_vector_type(4))) _Float16 f16x4;
typedef __attribute__((ext_vector_type(4))) float f32x4;

#define BB 32
#define TT 2048
#define CC 256
#define ESZ 256
#define GG 1024   // 4*es

// W2 split per gate-column, in h2-rows (128 total = 256 k-rows):
//   rows  0..79  -> VGPRs (80 u32 per column, 160 per thread)
//   rows 80..103 -> LDS   (6 uint4 chunks per column, 96 KB)
//   rows 104..127-> L2 stream (6 uint4 chunks per column, packed W2s)
#define MREG 80
#define NLDS 6
#define NSTR 6

// ---------------- helpers ----------------
__device__ __forceinline__ float fdot2u(u32 a, u32 b, float c) {
#if __has_builtin(__builtin_amdgcn_fdot2)
  return __builtin_amdgcn_fdot2(__builtin_bit_cast(h2v, a), __builtin_bit_cast(h2v, b), c, false);
#else
  h2v av = __builtin_bit_cast(h2v, a), bv = __builtin_bit_cast(h2v, b);
  return c + (float)av[0] * (float)bv[0] + (float)av[1] * (float)bv[1];
#endif
}

__device__ __forceinline__ float sigm_f(float x) {
  float e = __builtin_amdgcn_exp2f(x * -1.442695041f);
  return __builtin_amdgcn_rcpf(1.0f + e);
}
__device__ __forceinline__ float tanh_f(float x) {
  float e = __builtin_amdgcn_exp2f(x * 2.885390082f);  // exp(2x)
  return 1.0f - 2.0f * __builtin_amdgcn_rcpf(e + 1.0f);
}

// ---------------- kernel 0a: pack W2 (f32 [256][1024] -> h2-pair rows [128][1024]) ----------------
__global__ void k_pack_w2(const float* __restrict__ W2, u32* __restrict__ W2p) {
  int gid = blockIdx.x * 256 + threadIdx.x;   // m = gid>>10, j = gid&1023
  int m = gid >> 10, j = gid & 1023;
  _Float16 lo = (_Float16)W2[(size_t)(2 * m) * GG + j];
  _Float16 hi = (_Float16)W2[(size_t)(2 * m + 1) * GG + j];
  W2p[gid] = (u32)__builtin_bit_cast(u16, lo) | ((u32)__builtin_bit_cast(u16, hi) << 16);
}

// ---------------- kernel 0b: pack stream buffer W2s[c][col] = rows 104+4c..107+4c ----------------
__global__ void k_pack_stream(const u32* __restrict__ W2p, uint4* __restrict__ W2s) {
  int idx = blockIdx.x * 256 + threadIdx.x;   // 0..NSTR*1024-1
  int c = idx >> 10, col = idx & 1023;
  int m0 = (MREG + NLDS * 4) + 4 * c;
  uint4 v;
  v.x = W2p[(m0 + 0) * GG + col];
  v.y = W2p[(m0 + 1) * GG + col];
  v.z = W2p[(m0 + 2) * GG + col];
  v.w = W2p[(m0 + 3) * GG + col];
  W2s[idx] = v;
}

// ---------------- kernel 1: pre = x@W1 + b1 + b2  (f16 MFMA, out f16 [B*T][1024]) ----------------
__global__ __launch_bounds__(256, 2) void k_pre_gemm(
    const float* __restrict__ x, const float* __restrict__ W1,
    const float* __restrict__ b1, const float* __restrict__ b2,
    _Float16* __restrict__ pre) {
  __shared__ __attribute__((aligned(16))) _Float16 Al[128 * 36];
  __shared__ __attribute__((aligned(16))) _Float16 Bl[64 * 36];
  const int tid = threadIdx.x;
  const int lane = tid & 63, wv = tid >> 6;
  const int wr = wv >> 1, wc = wv & 1;
  const int rowBase = blockIdx.x * 128;
  const int colBase = blockIdx.y * 64;

  f32x4 acc[4][2];
#pragma unroll
  for (int mi = 0; mi < 4; ++mi)
#pragma unroll
    for (int ni = 0; ni < 2; ++ni) acc[mi][ni] = (f32x4){0.f, 0.f, 0.f, 0.f};

  for (int k0 = 0; k0 < 256; k0 += 32) {
#pragma unroll
    for (int i = 0; i < 4; ++i) {
      int fidx = tid + 256 * i;
      int row = fidx >> 3, kc = (fidx & 7) * 4;
      const float4 v = *(const float4*)(x + (size_t)(rowBase + row) * 256 + k0 + kc);
      f16x4 hv = { (_Float16)v.x, (_Float16)v.y, (_Float16)v.z, (_Float16)v.w };
      *(f16x4*)&Al[row * 36 + kc] = hv;
    }
#pragma unroll
    for (int i = 0; i < 8; ++i) {
      int idx = tid + 256 * i;
      int k = idx >> 6, n = idx & 63;
      Bl[n * 36 + k] = (_Float16)W1[(size_t)(k0 + k) * GG + colBase + n];
    }
    __syncthreads();

#pragma unroll
    for (int kk = 0; kk < 2; ++kk) {
      int ka = (lane >> 4) * 4 + kk * 16;
      f16x4 af[4], bf[2];
#pragma unroll
      for (int mi = 0; mi < 4; ++mi)
        af[mi] = *(const f16x4*)&Al[(wr * 64 + mi * 16 + (lane & 15)) * 36 + ka];
#pragma unroll
      for (int ni = 0; ni < 2; ++ni)
        bf[ni] = *(const f16x4*)&Bl[(wc * 32 + ni * 16 + (lane & 15)) * 36 + ka];
#pragma unroll
      for (int mi = 0; mi < 4; ++mi)
#pragma unroll
        for (int ni = 0; ni < 2; ++ni)
          acc[mi][ni] = __builtin_amdgcn_mfma_f32_16x16x16f16(af[mi], bf[ni], acc[mi][ni], 0, 0, 0);
    }
    __syncthreads();
  }

#pragma unroll
  for (int ni = 0; ni < 2; ++ni) {
    int col = colBase + wc * 32 + ni * 16 + (lane & 15);
    float bias = b1[col] + b2[col];
#pragma unroll
    for (int mi = 0; mi < 4; ++mi) {
      int r0 = rowBase + wr * 64 + mi * 16 + (lane >> 4) * 4;
#pragma unroll
      for (int rr = 0; rr < 4; ++rr)
        pre[(size_t)(r0 + rr) * GG + col] = (_Float16)(acc[mi][ni][rr] + bias);
    }
  }
}

// ---------------- kernel 2: the recurrence ----------------
// 32 blocks (one per batch), 512 threads (8 waves, EXACTLY 2/SIMD -> 256-VGPR budget).
// Thread t: j=t&255, half=t>>8; owns cols col0=j+half*512 (f/o), col1=col0+256 (i/ch).
// h distribution: per-lane ds_read_b32 (2 u32) + v_readlane -> SGPR feeding v_dot2
// (one readlane serves all 64 lanes AND both columns).
__global__ __launch_bounds__(512)
__attribute__((amdgpu_waves_per_eu(2, 2)))
void k_lstm_rec(
    const _Float16* __restrict__ pre, const u32* __restrict__ W2p,
    const uint4* __restrict__ W2s,
    const float* __restrict__ h0, const float* __restrict__ c0,
    float* __restrict__ out1, float* __restrict__ out2,
    float* __restrict__ hN, float* __restrict__ cN) {
  extern __shared__ __attribute__((aligned(16))) char smem[];
  uint4* W2Lw = (uint4*)smem;                                   // NLDS*1024 uint4 = 96 KB
  const uint4* W2L = (const uint4*)smem;
  _Float16* hbuf = (_Float16*)(smem + NLDS * 1024 * 16);        // 256 f16 = 512 B
  const u32* hrow = (const u32*)(smem + NLDS * 1024 * 16);      // h as 128 h2
  float* exch = (float*)(smem + NLDS * 1024 * 16 + 512);        // [4][260] f32

  const int t = threadIdx.x;
  const int b = blockIdx.x;
  const int j = t & 255, half = t >> 8;
  const int lane = t & 63;
  const int col0 = j + half * 512;
  const int col1 = col0 + 256;

  // register-resident W2 rows 0..MREG-1 for both columns
  u32 wA[MREG], wB[MREG];
#pragma unroll
  for (int m = 0; m < MREG; ++m) {
    wA[m] = W2p[m * GG + col0];
    wB[m] = W2p[m * GG + col1];
  }
#pragma unroll
  for (int m = 0; m < MREG; ++m) asm volatile("" : "+v"(wA[m]), "+v"(wB[m]));

  // LDS-resident rows MREG..MREG+4*NLDS-1: chunk c holds rows MREG+4c..MREG+4c+3
  for (int idx = t; idx < NLDS * 1024; idx += 512) {
    int c = idx >> 10, col = idx & 1023;
    int m0 = MREG + 4 * c;
    uint4 v;
    v.x = W2p[(m0 + 0) * GG + col];
    v.y = W2p[(m0 + 1) * GG + col];
    v.z = W2p[(m0 + 2) * GG + col];
    v.w = W2p[(m0 + 3) * GG + col];
    W2Lw[idx] = v;
  }

  float creg = 0.f, hlast = 0.f;
  if (!half) {
    hbuf[j] = (_Float16)h0[b * ESZ + j];
    creg = c0[b * ESZ + j];
  }
  __syncthreads();

  const _Float16* preB = pre + (size_t)b * TT * GG;
  _Float16 q0 = preB[col0], q1 = preB[col1];

  for (int s = 0; s < TT; ++s) {
    // per-lane h (conflict-free b32); readlane distributes below
    u32 hv0 = hrow[lane];
    u32 hv1 = hrow[64 + lane];

    // issue this step's L2-stream loads early (data is step-invariant, L2-hot)
    uint4 sA[NSTR], sB[NSTR];
#pragma unroll
    for (int i = 0; i < NSTR; ++i) {
      sA[i] = W2s[i * 1024 + col0];
      sB[i] = W2s[i * 1024 + col1];
    }

    float a0 = (float)q0, a1 = (float)q1;
    if (s + 1 < TT) {  // prefetch next step's pre
      const _Float16* pn = preB + (size_t)(s + 1) * GG;
      q0 = pn[col0];
      q1 = pn[col1];
    }
    float p0 = 0.f, p1 = 0.f;

    // REG part: h2 rows 0..63 (hv0 lanes 0..63)
#pragma unroll
    for (int m = 0; m < 64; ++m) {
      u32 hm = (u32)__builtin_amdgcn_readlane((int)hv0, m);
      a0 = fdot2u(hm, wA[m], a0);
      a1 = fdot2u(hm, wB[m], a1);
    }
    // REG part: rows 64..79 (hv1 lanes 0..15)
#pragma unroll
    for (int i = 0; i < MREG - 64; ++i) {
      u32 hm = (u32)__builtin_amdgcn_readlane((int)hv1, i);
      p0 = fdot2u(hm, wA[64 + i], p0);
      p1 = fdot2u(hm, wB[64 + i], p1);
    }
    // LDS part: rows 80..103 (hv1 lanes 16..39)
#pragma unroll
    for (int c = 0; c < NLDS; ++c) {
      uint4 la = W2L[c * 1024 + col0];
      uint4 lb = W2L[c * 1024 + col1];
      u32 lax[4] = {la.x, la.y, la.z, la.w};
      u32 lbx[4] = {lb.x, lb.y, lb.z, lb.w};
#pragma unroll
      for (int r = 0; r < 4; ++r) {
        u32 hm = (u32)__builtin_amdgcn_readlane((int)hv1, (MREG - 64) + 4 * c + r);
        p0 = fdot2u(hm, lax[r], p0);
        p1 = fdot2u(hm, lbx[r], p1);
      }
    }
    // STREAM part: rows 104..127 (hv1 lanes 40..63)
#pragma unroll
    for (int c = 0; c < NSTR; ++c) {
      u32 sax[4] = {sA[c].x, sA[c].y, sA[c].z, sA[c].w};
      u32 sbx[4] = {sB[c].x, sB[c].y, sB[c].z, sB[c].w};
#pragma unroll
      for (int r = 0; r < 4; ++r) {
        u32 hm = (u32)__builtin_amdgcn_readlane((int)hv1, (MREG - 64) + NLDS * 4 + 4 * c + r);
        a0 = fdot2u(hm, sax[r], a0);
        a1 = fdot2u(hm, sbx[r], a1);
      }
    }
    a0 += p0;
    a1 += p1;

    // activations: half0 -> (f, i) both sigmoid; half1 -> (o sigmoid, ch tanh)
    float g0 = sigm_f(a0);
    float g1 = half ? tanh_f(a1) : sigm_f(a1);
    exch[(half * 2 + 0) * 260 + j] = g0;
    exch[(half * 2 + 1) * 260 + j] = g1;
    __syncthreads();  // B1: exch ready; all h reads of this step done

    if (!half) {
      float fg = exch[0 * 260 + j];
      float ig = exch[1 * 260 + j];
      float og = exch[2 * 260 + j];
      float ch = exch[3 * 260 + j];
      creg = fg * creg + ig * ch;
      float hv = og * tanh_f(creg);
      hlast = hv;
      out1[(size_t)b * TT * ESZ + (size_t)s * ESZ + j] = hv;   // [B, T*es]
      out2[(size_t)s * (BB * ESZ) + b * ESZ + j] = hv;         // [T, B, es]
      hbuf[j] = (_Float16)hv;
    }
    __syncthreads();  // B2: next step's h visible
  }

  if (!half) {
    hN[b * ESZ + j] = hlast;
    cN[b * ESZ + j] = creg;
  }
}

// ---------------- launch ----------------
extern "C" void kernel_launch(void* const* d_in, const int* in_sizes, int n_in,
                              void* d_out, int out_size, void* d_ws, size_t ws_size,
                              hipStream_t stream) {
  const float* x  = (const float*)d_in[0];
  const float* h0 = (const float*)d_in[1];
  const float* c0 = (const float*)d_in[2];
  const float* W1 = (const float*)d_in[3];
  const float* W2 = (const float*)d_in[4];
  const float* b1 = (const float*)d_in[5];
  const float* b2 = (const float*)d_in[6];

  float* out1 = (float*)d_out;
  float* out2 = out1 + (size_t)BB * TT * ESZ;
  float* hN   = out2 + (size_t)BB * TT * ESZ;
  float* cN   = hN + BB * ESZ;

  _Float16* pre = (_Float16*)d_ws;                                  // 128 MB
  u32* W2p = (u32*)((char*)d_ws + (size_t)BB * TT * GG * 2);        // 512 KB
  uint4* W2s = (uint4*)((char*)W2p + 128 * GG * 4);                 // 96 KB

  k_pack_w2<<<512, 256, 0, stream>>>(W2, W2p);
  k_pack_stream<<<NSTR * 4, 256, 0, stream>>>(W2p, W2s);
  k_pre_gemm<<<dim3(512, 16), 256, 0, stream>>>(x, W1, b1, b2, pre);

  const int ldsBytes = NLDS * 1024 * 16 + 512 + 4 * 260 * 4;  // 96KB W2 + hbuf + exch
  hipFuncSetAttribute((const void*)k_lstm_rec, hipFuncAttributeMaxDynamicSharedMemorySize, ldsBytes);
  k_lstm_rec<<<BB, 512, ldsBytes, stream>>>(pre, W2p, W2s, h0, c0, out1, out2, hN, cN);
}

// Round 5
// 4454.878 us; speedup vs baseline: 1.4508x; 1.1741x over previous
//
#include <hip/hip_runtime.h>

typedef unsigned int u32;
typedef unsigned short u16;
typedef __attribute__((ext_vector_type(2))) _Float16 h2v;
typedef __attribute__((ext_vector_type(4))) _Float16 f16x4;
typedef __attribute__((ext_vector_type(4))) float f32x4;

#define BB 32
#define TT 2048
#define CC 256
#define ESZ 256
#define GG 1024   // 4*es

// W2 split per gate-column, in h2-rows (128 total = 256 k-rows):
//   rows  0..39   -> VGPRs (40 u32 per column, 80 per thread)       [MREG]
//   rows 40..95   -> L2 stream, 14 chunks of 4 rows (229 KB/step)   [NSTR]
//   rows 96..127  -> LDS, 8 chunks of 4 rows (128 KB)               [NLDS]
#define MREG 40
#define NSTR 14
#define NLDS 8

// ---------------- helpers ----------------
__device__ __forceinline__ float fdot2u(u32 a, u32 b, float c) {
#if __has_builtin(__builtin_amdgcn_fdot2)
  return __builtin_amdgcn_fdot2(__builtin_bit_cast(h2v, a), __builtin_bit_cast(h2v, b), c, false);
#else
  h2v av = __builtin_bit_cast(h2v, a), bv = __builtin_bit_cast(h2v, b);
  return c + (float)av[0] * (float)bv[0] + (float)av[1] * (float)bv[1];
#endif
}

__device__ __forceinline__ float sigm_f(float x) {
  float e = __builtin_amdgcn_exp2f(x * -1.442695041f);
  return __builtin_amdgcn_rcpf(1.0f + e);
}
__device__ __forceinline__ float tanh_f(float x) {
  float e = __builtin_amdgcn_exp2f(x * 2.885390082f);  // exp(2x)
  return 1.0f - 2.0f * __builtin_amdgcn_rcpf(e + 1.0f);
}

// readlane of the right h register for a compile-time h2-row
__device__ __forceinline__ u32 h_row(u32 hv0, u32 hv1, int row) {
  return (row < 64) ? (u32)__builtin_amdgcn_readlane((int)hv0, row)
                    : (u32)__builtin_amdgcn_readlane((int)hv1, row - 64);
}

// ---------------- kernel 0a: pack W2 (f32 [256][1024] -> h2 rows [128][1024]) ----------------
__global__ void k_pack_w2(const float* __restrict__ W2, u32* __restrict__ W2p) {
  int gid = blockIdx.x * 256 + threadIdx.x;   // m = gid>>10, j = gid&1023
  int m = gid >> 10, j = gid & 1023;
  _Float16 lo = (_Float16)W2[(size_t)(2 * m) * GG + j];
  _Float16 hi = (_Float16)W2[(size_t)(2 * m + 1) * GG + j];
  W2p[gid] = (u32)__builtin_bit_cast(u16, lo) | ((u32)__builtin_bit_cast(u16, hi) << 16);
}

// ---------------- kernel 0b: pack stream buffer: chunk c = h2-rows MREG+4c..MREG+4c+3 ----------------
__global__ void k_pack_stream(const u32* __restrict__ W2p, uint4* __restrict__ W2s) {
  int idx = blockIdx.x * 256 + threadIdx.x;   // 0..NSTR*1024-1
  int c = idx >> 10, col = idx & 1023;
  int m0 = MREG + 4 * c;
  uint4 v;
  v.x = W2p[(m0 + 0) * GG + col];
  v.y = W2p[(m0 + 1) * GG + col];
  v.z = W2p[(m0 + 2) * GG + col];
  v.w = W2p[(m0 + 3) * GG + col];
  W2s[idx] = v;
}

// ---------------- kernel 1: pre = x@W1 + b1 + b2  (f16 MFMA, out f16 [B*T][1024]) ----------------
__global__ __launch_bounds__(256, 2) void k_pre_gemm(
    const float* __restrict__ x, const float* __restrict__ W1,
    const float* __restrict__ b1, const float* __restrict__ b2,
    _Float16* __restrict__ pre) {
  __shared__ __attribute__((aligned(16))) _Float16 Al[128 * 36];
  __shared__ __attribute__((aligned(16))) _Float16 Bl[64 * 36];
  const int tid = threadIdx.x;
  const int lane = tid & 63, wv = tid >> 6;
  const int wr = wv >> 1, wc = wv & 1;
  const int rowBase = blockIdx.x * 128;
  const int colBase = blockIdx.y * 64;

  f32x4 acc[4][2];
#pragma unroll
  for (int mi = 0; mi < 4; ++mi)
#pragma unroll
    for (int ni = 0; ni < 2; ++ni) acc[mi][ni] = (f32x4){0.f, 0.f, 0.f, 0.f};

  for (int k0 = 0; k0 < 256; k0 += 32) {
#pragma unroll
    for (int i = 0; i < 4; ++i) {
      int fidx = tid + 256 * i;
      int row = fidx >> 3, kc = (fidx & 7) * 4;
      const float4 v = *(const float4*)(x + (size_t)(rowBase + row) * 256 + k0 + kc);
      f16x4 hv = { (_Float16)v.x, (_Float16)v.y, (_Float16)v.z, (_Float16)v.w };
      *(f16x4*)&Al[row * 36 + kc] = hv;
    }
#pragma unroll
    for (int i = 0; i < 8; ++i) {
      int idx = tid + 256 * i;
      int k = idx >> 6, n = idx & 63;
      Bl[n * 36 + k] = (_Float16)W1[(size_t)(k0 + k) * GG + colBase + n];
    }
    __syncthreads();

#pragma unroll
    for (int kk = 0; kk < 2; ++kk) {
      int ka = (lane >> 4) * 4 + kk * 16;
      f16x4 af[4], bf[2];
#pragma unroll
      for (int mi = 0; mi < 4; ++mi)
        af[mi] = *(const f16x4*)&Al[(wr * 64 + mi * 16 + (lane & 15)) * 36 + ka];
#pragma unroll
      for (int ni = 0; ni < 2; ++ni)
        bf[ni] = *(const f16x4*)&Bl[(wc * 32 + ni * 16 + (lane & 15)) * 36 + ka];
#pragma unroll
      for (int mi = 0; mi < 4; ++mi)
#pragma unroll
        for (int ni = 0; ni < 2; ++ni)
          acc[mi][ni] = __builtin_amdgcn_mfma_f32_16x16x16f16(af[mi], bf[ni], acc[mi][ni], 0, 0, 0);
    }
    __syncthreads();
  }

#pragma unroll
  for (int ni = 0; ni < 2; ++ni) {
    int col = colBase + wc * 32 + ni * 16 + (lane & 15);
    float bias = b1[col] + b2[col];
#pragma unroll
    for (int mi = 0; mi < 4; ++mi) {
      int r0 = rowBase + wr * 64 + mi * 16 + (lane >> 4) * 4;
#pragma unroll
      for (int rr = 0; rr < 4; ++rr)
        pre[(size_t)(r0 + rr) * GG + col] = (_Float16)(acc[mi][ni][rr] + bias);
    }
  }
}

// ---------------- kernel 2: the recurrence ----------------
// 32 blocks (one per batch), 512 threads (8 waves, 2/SIMD).
// Thread t: j=t&255, half=t>>8; cols col0=j+half*512 (f/o), col1=col0+256 (i/ch).
// Designed to EXACTLY fit the 128-VGPR grant: 80 weight regs + 16 stream-staging
// + ~28 working. Raw s_barrier (lgkmcnt only) so pre-prefetch/out-stores span steps.
__global__ __launch_bounds__(512)
__attribute__((amdgpu_waves_per_eu(2, 2)))
void k_lstm_rec(
    const _Float16* __restrict__ pre, const u32* __restrict__ W2p,
    const uint4* __restrict__ W2s,
    const float* __restrict__ h0, const float* __restrict__ c0,
    float* __restrict__ out1, float* __restrict__ out2,
    float* __restrict__ hN, float* __restrict__ cN) {
  extern __shared__ __attribute__((aligned(16))) char smem[];
  uint4* W2Lw = (uint4*)smem;                                   // NLDS*1024 uint4 = 128 KB
  const uint4* W2L = (const uint4*)smem;
  _Float16* hbuf = (_Float16*)(smem + NLDS * 1024 * 16);        // 256 f16 = 512 B
  const u32* hrow = (const u32*)(smem + NLDS * 1024 * 16);      // h as 128 h2
  float* exch = (float*)(smem + NLDS * 1024 * 16 + 512);        // [4][260] f32

  const int t = threadIdx.x;
  const int b = blockIdx.x;
  const int j = t & 255, half = t >> 8;
  const int lane = t & 63;
  const int col0 = j + half * 512;
  const int col1 = col0 + 256;

  // register-resident W2 rows 0..MREG-1 for both columns
  u32 wA[MREG], wB[MREG];
#pragma unroll
  for (int m = 0; m < MREG; ++m) {
    wA[m] = W2p[m * GG + col0];
    wB[m] = W2p[m * GG + col1];
  }
#pragma unroll
  for (int m = 0; m < MREG; ++m) asm volatile("" : "+v"(wA[m]), "+v"(wB[m]));

  // LDS-resident rows 96..127: chunk c holds rows 96+4c..96+4c+3
  for (int idx = t; idx < NLDS * 1024; idx += 512) {
    int c = idx >> 10, col = idx & 1023;
    int m0 = MREG + 4 * NSTR + 4 * c;
    uint4 v;
    v.x = W2p[(m0 + 0) * GG + col];
    v.y = W2p[(m0 + 1) * GG + col];
    v.z = W2p[(m0 + 2) * GG + col];
    v.w = W2p[(m0 + 3) * GG + col];
    W2Lw[idx] = v;
  }

  float creg = 0.f, hlast = 0.f;
  if (!half) {
    hbuf[j] = (_Float16)h0[b * ESZ + j];
    creg = c0[b * ESZ + j];
  }
  __syncthreads();

  const _Float16* preB = pre + (size_t)b * TT * GG;
  const uint4* sBase0 = W2s + col0;
  const uint4* sBase1 = W2s + col1;
  _Float16 q0 = preB[col0], q1 = preB[col1];

  for (int s = 0; s < TT; ++s) {
    // per-lane h (conflict-free b32); readlane distributes below
    u32 hv0 = hrow[lane];
    u32 hv1 = hrow[64 + lane];

    // stream pipeline prologue: issue chunks 0,1 (depth-2)
    uint4 stA[2], stB[2];
    stA[0] = sBase0[0 * 1024]; stB[0] = sBase1[0 * 1024];
    stA[1] = sBase0[1 * 1024]; stB[1] = sBase1[1 * 1024];

    float a0 = (float)q0, a1 = (float)q1;
    if (s + 1 < TT) {  // prefetch next step's pre (spans the raw barriers)
      const _Float16* pn = preB + (size_t)(s + 1) * GG;
      q0 = pn[col0];
      q1 = pn[col1];
    }
    float p0 = 0.f, p1 = 0.f;

    // REG part: rows 0..MREG-1 (covers L2 latency of the first stream chunks)
#pragma unroll
    for (int m = 0; m < MREG; ++m) {
      u32 hm = (u32)__builtin_amdgcn_readlane((int)hv0, m);
      a0 = fdot2u(hm, wA[m], a0);
      a1 = fdot2u(hm, wB[m], a1);
    }

    // STREAM part: rows MREG..MREG+4*NSTR-1, depth-2 pipelined
#pragma unroll
    for (int c = 0; c < NSTR; ++c) {
      uint4 wa = stA[c & 1], wb = stB[c & 1];
      if (c + 2 < NSTR) {
        stA[c & 1] = sBase0[(c + 2) * 1024];
        stB[c & 1] = sBase1[(c + 2) * 1024];
      }
      u32 wax[4] = {wa.x, wa.y, wa.z, wa.w};
      u32 wbx[4] = {wb.x, wb.y, wb.z, wb.w};
#pragma unroll
      for (int r = 0; r < 4; ++r) {
        u32 hm = h_row(hv0, hv1, MREG + 4 * c + r);
        p0 = fdot2u(hm, wax[r], p0);
        p1 = fdot2u(hm, wbx[r], p1);
      }
    }

    // LDS part: rows 96..127
#pragma unroll
    for (int c = 0; c < NLDS; ++c) {
      uint4 la = W2L[c * 1024 + col0];
      uint4 lb = W2L[c * 1024 + col1];
      u32 lax[4] = {la.x, la.y, la.z, la.w};
      u32 lbx[4] = {lb.x, lb.y, lb.z, lb.w};
#pragma unroll
      for (int r = 0; r < 4; ++r) {
        u32 hm = (u32)__builtin_amdgcn_readlane((int)hv1, 32 + 4 * c + r);
        a0 = fdot2u(hm, lax[r], a0);
        a1 = fdot2u(hm, lbx[r], a1);
      }
    }
    a0 += p0;
    a1 += p1;

    // activations: half0 -> (f, i) sigmoid; half1 -> (o sigmoid, ch tanh)
    float g0 = sigm_f(a0);
    float g1 = half ? tanh_f(a1) : sigm_f(a1);
    exch[(half * 2 + 0) * 260 + j] = g0;
    exch[(half * 2 + 1) * 260 + j] = g1;

    // B1: exch visible; LDS-only drain (no vmcnt!) so prefetch/stores overlap
    asm volatile("s_waitcnt lgkmcnt(0)" ::: "memory");
    __builtin_amdgcn_s_barrier();

    if (!half) {
      float fg = exch[0 * 260 + j];
      float ig = exch[1 * 260 + j];
      float og = exch[2 * 260 + j];
      float ch = exch[3 * 260 + j];
      creg = fg * creg + ig * ch;
      float hv = og * tanh_f(creg);
      hlast = hv;
      out1[(size_t)b * TT * ESZ + (size_t)s * ESZ + j] = hv;   // [B, T*es]
      out2[(size_t)s * (BB * ESZ) + b * ESZ + j] = hv;         // [T, B, es]
      hbuf[j] = (_Float16)hv;
    }

    // B2: next step's h visible
    asm volatile("s_waitcnt lgkmcnt(0)" ::: "memory");
    __builtin_amdgcn_s_barrier();
  }

  if (!half) {
    hN[b * ESZ + j] = hlast;
    cN[b * ESZ + j] = creg;
  }
}

// ---------------- launch ----------------
extern "C" void kernel_launch(void* const* d_in, const int* in_sizes, int n_in,
                              void* d_out, int out_size, void* d_ws, size_t ws_size,
                              hipStream_t stream) {
  const float* x  = (const float*)d_in[0];
  const float* h0 = (const float*)d_in[1];
  const float* c0 = (const float*)d_in[2];
  const float* W1 = (const float*)d_in[3];
  const float* W2 = (const float*)d_in[4];
  const float* b1 = (const float*)d_in[5];
  const float* b2 = (const float*)d_in[6];

  float* out1 = (float*)d_out;
  float* out2 = out1 + (size_t)BB * TT * ESZ;
  float* hN   = out2 + (size_t)BB * TT * ESZ;
  float* cN   = hN + BB * ESZ;

  _Float16* pre = (_Float16*)d_ws;                                  // 128 MB
  u32* W2p = (u32*)((char*)d_ws + (size_t)BB * TT * GG * 2);        // 512 KB
  uint4* W2s = (uint4*)((char*)W2p + 128 * GG * 4);                 // 229 KB

  k_pack_w2<<<512, 256, 0, stream>>>(W2, W2p);
  k_pack_stream<<<NSTR * 4, 256, 0, stream>>>(W2p, W2s);
  k_pre_gemm<<<dim3(512, 16), 256, 0, stream>>>(x, W1, b1, b2, pre);

  const int ldsBytes = NLDS * 1024 * 16 + 512 + 4 * 260 * 4;  // 128KB W2 + hbuf + exch
  hipFuncSetAttribute((const void*)k_lstm_rec, hipFuncAttributeMaxDynamicSharedMemorySize, ldsBytes);
  k_lstm_rec<<<BB, 512, ldsBytes, stream>>>(pre, W2p, W2s, h0, c0, out1, out2, hN, cN);
}